// Round 9
// baseline (80.253 us; speedup 1.0000x reference)
//
#include <hip/hip_runtime.h>

#define NB     32
#define NATOM  48
#define NGRID  128
#define KT     8                          /* grid points per block */
#define NTHR   768                        /* 12 waves: thread = (n, kk, h) */

#define MBTR_ELEMS (NB*16*NGRID)          /* 65536 */
#define DIV_PER_B  (16*NGRID*NATOM*3)     /* 294912 */
#define PANE       (NGRID*NATOM*3)        /* 18432 floats per (e1,e2) pane */
#define MSTRIDE    49                     /* padded n-stride for M table */
#define PSTRIDE    17                     /* odd stride -> conflict-free */

// Fused MBTR fwd+div, SPLIT-M for 2x occupancy.
// R5-R8 A/B history: issue-count cuts neutral, chain-shortening -1us,
// parallelism halving 0/+4us -> the kernel is latency-bound and capped at
// 12 waves/CU because total threads == B*G*N. This version doubles wave
// count (768-thread blocks): thread (n,kk,h) sums alternate atoms of each
// species segment (24 iters instead of 48), halves get combined through a
// conflict-free LDS table (Part[384][17]). Barriers never drain stores:
// div stores (h=0 waves) and the mbtr reduction (h=1 waves 6..7) run
// concurrently after the last barrier.
// Kept from R8: species-sorted static-address pos_s (no LDS indirection),
// static-e segmented accumulators (R4 lesson), wf+coef folded into exp2,
// float3 register-direct div stores.
__global__ __launch_bounds__(NTHR)
void mbtr_fused(const float* __restrict__ r, const int* __restrict__ z,
                const float* __restrict__ grid, float* __restrict__ out)
{
    const int kt = blockIdx.x, b = blockIdx.y, t = threadIdx.x;
    const int k0 = kt * KT;

    __shared__ float4 pos_s[NATOM + 1];   /* species-sorted; +1 pad */
    __shared__ int    zl[NATOM];
    __shared__ int    soff_s[5];
    __shared__ float  znpos[NATOM * 3];   /* unsorted positions for rn */
    __shared__ float  Mrec[KT * 4 * MSTRIDE];   /* [kk][e][49] */
    __shared__ float  Part[384 * PSTRIDE];      /* h=1 partials, odd stride */

    // ---- setup: wave 0 loads atoms, scatters them species-sorted ----
    if (t < 64) {
        const bool isatom = (t < NATOM);
        int myz = 999;
        float rx = 0.f, ry = 0.f, rz = 0.f;
        if (isatom) {
            myz = z[t];
            zl[t] = myz;
            const float* rp = r + ((size_t)b * NATOM + t) * 3;
            rx = rp[0]; ry = rp[1]; rz = rp[2];
            znpos[t * 3 + 0] = rx; znpos[t * 3 + 1] = ry; znpos[t * 3 + 2] = rz;
        }
        const unsigned long long m0 = __ballot(myz == 0);
        const unsigned long long m1 = __ballot(myz == 1);
        const unsigned long long m2 = __ballot(myz == 2);
        const unsigned long long m3 = __ballot(myz == 3);
        const int c0 = __popcll(m0), c1 = __popcll(m1), c2 = __popcll(m2);
        if (isatom) {
            const unsigned long long mm = (myz == 0) ? m0 : (myz == 1) ? m1
                                        : (myz == 2) ? m2 : m3;
            const int base = (myz == 0) ? 0 : (myz == 1) ? c0
                           : (myz == 2) ? c0 + c1 : c0 + c1 + c2;
            const int rank = __popcll(mm & ((1ull << t) - 1ull));
            pos_s[base + rank] = make_float4(rx, ry, rz, (float)t);
        }
        if (t == 0) {
            soff_s[0] = 0; soff_s[1] = c0; soff_s[2] = c0 + c1;
            soff_s[3] = c0 + c1 + c2; soff_s[4] = NATOM;
            pos_s[NATOM] = make_float4(0.f, 0.f, 0.f, -1.f);
        }
    }
    __syncthreads();

    // ---- phase 1: thread = (n, kk, h); h sums alternate atoms ----
    const int h  = (t < 384) ? 0 : 1;       // wave-uniform (waves 0-5 vs 6-11)
    const int tt = t - 384 * h;
    const int n  = tt % NATOM;
    const int kk = tt / NATOM;              // 0..7
    const float dx   = grid[1] - grid[0];
    const float coef = dx * 7.9788456080286535f;     // dx*20/sqrt(2pi)
    const float mlc  = -__log2f(coef);
    const float isc  = 16.986436005760382f;          // 20*sqrt(log2e/2)
    const float tBc  = 23.548200452219559f;          // 20/sqrt(log2e/2)
    const float l2e  = 1.4426950408889634f;
    const float gk   = grid[k0 + kk] * isc;
    const float nf   = (float)n;

    float A[4][3] = {{0.f}};
    float M[4]    = {0.f};
    const float rnx = znpos[n * 3 + 0];
    const float rny = znpos[n * 3 + 1];
    const float rnz = znpos[n * 3 + 2];
    const int   zn  = zl[n];
    int so[5];
    #pragma unroll
    for (int e = 0; e < 5; ++e) so[e] = soff_s[e];

    #pragma unroll
    for (int e = 0; e < 4; ++e) {           // e STATIC -> A[e] in registers
        #pragma unroll 2
        for (int i = so[e] + h; i < so[e + 1]; i += 2) {
            const float4 rm = pos_s[i];     // static-address broadcast read
            const float ddx = rnx - rm.x, ddy = rny - rm.y, ddz = rnz - rm.z;
            float d2 = ddx*ddx + ddy*ddy + ddz*ddz;
            const bool self = (rm.w == nf);
            d2 = self ? 1.0f : d2;                        // rsq NaN guard
            const float gf  = __builtin_amdgcn_rsqf(d2);  // 1/d
            const float c1  = gf * isc;
            const float d   = d2 * gf;
            float base = fmaf(d, l2e, mlc);               // wf & coef folded
            base = self ? 1e30f : base;                   // kill self pair
            const float bq  = (gf * gf) * tBc;
            const float tt2 = gk - c1;
            const float ex  = exp2f(-fmaf(tt2, tt2, base)); // coef*wf*gv
            M[e] += ex;
            const float p   = ex * fmaf(tt2, bq, 1.0f);
            A[e][0] = fmaf(-p, gf * ddx, A[e][0]);
            A[e][1] = fmaf(-p, gf * ddy, A[e][1]);
            A[e][2] = fmaf(-p, gf * ddz, A[e][2]);
        }
    }

    // ---- combine halves: h=1 publishes, h=0 reduces ----
    if (h == 1) {
        float* pp = Part + tt * PSTRIDE;
        #pragma unroll
        for (int e = 0; e < 4; ++e) {
            pp[e * 3 + 0] = A[e][0];
            pp[e * 3 + 1] = A[e][1];
            pp[e * 3 + 2] = A[e][2];
            pp[12 + e]    = M[e];
        }
    }
    __syncthreads();
    if (h == 0) {
        const float* pp = Part + tt * PSTRIDE;
        #pragma unroll
        for (int e = 0; e < 4; ++e) {
            A[e][0] += pp[e * 3 + 0];
            A[e][1] += pp[e * 3 + 1];
            A[e][2] += pp[e * 3 + 2];
            M[e]    += pp[12 + e];
        }
        float* mr = Mrec + kk * (4 * MSTRIDE) + n;
        #pragma unroll
        for (int e = 0; e < 4; ++e) mr[e * MSTRIDE] = M[e];
    }
    __syncthreads();    // LDS-only drain: no global stores in flight yet

    if (h == 0) {
        // ---- div stores straight from registers (h=0 waves) ----
        float* basep = out + MBTR_ELEMS + (size_t)b * DIV_PER_B
                     + (size_t)(k0 + kk) * 144 + n * 3;
        #pragma unroll
        for (int e1 = 0; e1 < 4; ++e1) {
            const bool s1 = (zn == e1);
            #pragma unroll
            for (int e2 = 0; e2 < 4; ++e2) {
                const bool s2 = (zn == e2);
                float3 v;
                v.x = (s1 ? A[e2][0] : 0.f) + (s2 ? A[e1][0] : 0.f);
                v.y = (s1 ? A[e2][1] : 0.f) + (s2 ? A[e1][1] : 0.f);
                v.z = (s1 ? A[e2][2] : 0.f) + (s2 ? A[e1][2] : 0.f);
                *(float3*)(basep + (e1 * 4 + e2) * PANE) = v;
            }
        }
    } else if (tt < 128) {
        // ---- mbtr reduction on h=1 waves 6..7, concurrent with stores ----
        const int mpane = tt >> 3, mkk = tt & 7;
        const int me1 = mpane >> 2, me2 = mpane & 3;
        const float* tr2 = Mrec + mkk * (4 * MSTRIDE) + me2 * MSTRIDE;
        float s = 0.f;
        #pragma unroll
        for (int nn = 0; nn < NATOM; ++nn)
            s += (zl[nn] == me1) ? tr2[nn] : 0.f;
        out[(size_t)b * 2048 + mpane * NGRID + k0 + mkk] = s;
    }
}

extern "C" void kernel_launch(void* const* d_in, const int* in_sizes, int n_in,
                              void* d_out, int out_size, void* d_ws, size_t ws_size,
                              hipStream_t stream)
{
    const float* r    = (const float*)d_in[0];
    const int*   z    = (const int*)  d_in[1];
    const float* grid = (const float*)d_in[2];
    float* out = (float*)d_out;
    (void)d_ws; (void)ws_size;

    mbtr_fused<<<dim3(NGRID / KT, NB), NTHR, 0, stream>>>(r, z, grid, out);
}